// Round 9
// baseline (214.774 us; speedup 1.0000x reference)
//
#include <hip/hip_runtime.h>

// x [B, NF, T] f32, durations [B, N] int32 -> out [B, NF, N] f32
// out[b,f,n] = mean of nonzero x[b,f,ts..te) (0 if none), ts/te from cumsum(durations)
#define BB 64
#define NF 64
#define TT 8192
#define NN 1024
#define NC (TT / 4)                 // 2048 chunks of 4 floats
#define PAD(c) ((c) + ((c) >> 3))   // scan-read addr 9t+j -> 2-way max (free)

// One block per (b,nf) row. No raw-row LDS: boundary remainders (<=3 elems)
// re-read from global while the row is L1/L2-hot. LDS ~18.5 KB -> 5-6 blocks/CU.
// 3 barriers total.
__global__ __launch_bounds__(256) void fused_kernel(const float* __restrict__ x,
                                                    const int* __restrict__ dur,
                                                    float* __restrict__ out) {
    const int row  = blockIdx.x;          // b*NF + nf
    const int bat  = row >> 6;            // NF = 64
    const int t    = threadIdx.x;
    const int lane = t & 63;
    const int w    = t >> 6;

    __shared__ float S[PAD(NC) + 1];      // chunk sums -> exclusive prefix (+ grand total)
    __shared__ float C[PAD(NC) + 1];      // chunk nonzero counts -> prefix
    __shared__ int   wsi[4];
    __shared__ float wsf[4], wcf[4];

    // ---- issue all global loads first ----
    const float4* __restrict__ xv = (const float4*)(x + (size_t)row * TT);
    float4 stage[8];
#pragma unroll
    for (int k = 0; k < 8; ++k) stage[k] = xv[t + (k << 8)];
    const int4 d4 = ((const int4*)(dur + bat * NN))[t];

    // ---- duration shfl-scan while row loads are in flight ----
    const int i0 = d4.x, i1 = i0 + d4.y, i2 = i1 + d4.z, i3 = i2 + d4.w;
    int wsum = i3;
#pragma unroll
    for (int d = 1; d < 64; d <<= 1) {
        int u = __shfl_up(wsum, d, 64);
        if (lane >= d) wsum += u;
    }
    if (lane == 63) wsi[w] = wsum;

    // ---- chunk sums/counts from staged regs -> padded LDS ----
#pragma unroll
    for (int k = 0; k < 8; ++k) {
        const int c = t + (k << 8);
        const float4 v = stage[k];
        S[PAD(c)] = v.x + v.y + v.z + v.w;
        C[PAD(c)] = (v.x != 0.f) + (v.y != 0.f) + (v.z != 0.f) + (v.w != 0.f);
    }
    __syncthreads();                      // covers wsi AND S/C staging

    // ---- this thread's 5 token boundaries, in registers ----
    int boff = 0;
#pragma unroll
    for (int i = 0; i < 4; ++i) if (i < w) boff += wsi[i];
    const int eb = boff + wsum - i3;
    const int bnd[5] = { eb, eb + i0, eb + i1, eb + i2, eb + i3 };

    // ---- block exclusive scan over 2048 chunks; thread owns [8t, 8t+8) ----
    float sv[8], cv[8];
    float fs = 0.f, cs = 0.f;
#pragma unroll
    for (int j = 0; j < 8; ++j) {
        const int c = (t << 3) + j;       // PAD(c) = 9t+j
        fs += S[PAD(c)]; cs += C[PAD(c)];
        sv[j] = fs; cv[j] = cs;           // within-thread inclusive
    }
    float ws = fs, wc = cs;
#pragma unroll
    for (int d = 1; d < 64; d <<= 1) {
        float uf = __shfl_up(ws, d, 64);
        float uc = __shfl_up(wc, d, 64);
        if (lane >= d) { ws += uf; wc += uc; }
    }
    if (lane == 63) { wsf[w] = ws; wcf[w] = wc; }
    __syncthreads();
    float woff = 0.f, coff = 0.f;
#pragma unroll
    for (int i = 0; i < 4; ++i) if (i < w) { woff += wsf[i]; coff += wcf[i]; }
    const float fb = woff + (ws - fs);    // exclusive base for chunk 8t
    const float cb = coff + (wc - cs);
#pragma unroll
    for (int j = 0; j < 8; ++j) {
        const int c = (t << 3) + j;
        S[PAD(c)] = fb + (j ? sv[j - 1] : 0.f);
        C[PAD(c)] = cb + (j ? cv[j - 1] : 0.f);
    }
    if (t == 255) { S[PAD(NC)] = woff + ws; C[PAD(NC)] = coff + wc; }
    __syncthreads();

    // ---- eval 5 boundary prefixes (remainder from cache-hot global) -> 4 means ----
    float ps[5], pk[5];
#pragma unroll
    for (int j = 0; j < 5; ++j) {
        const int p = bnd[j];             // in [0, T]
        const int g = p >> 2, r = p & 3;
        float s = S[PAD(g)], c = C[PAD(g)];   // p==T -> grand-total slot, r==0
        if (r) {
            const float4 v = xv[g];       // L1/L2-hot re-read
            s += v.x; c += (v.x != 0.f);
            if (r > 1) { s += v.y; c += (v.y != 0.f); }
            if (r > 2) { s += v.z; c += (v.z != 0.f); }
        }
        ps[j] = s; pk[j] = c;
    }
    float4 o;
    {
        const float s0 = ps[1] - ps[0], c0 = pk[1] - pk[0];
        const float s1 = ps[2] - ps[1], c1 = pk[2] - pk[1];
        const float s2 = ps[3] - ps[2], c2 = pk[3] - pk[2];
        const float s3 = ps[4] - ps[3], c3 = pk[4] - pk[3];
        o.x = (c0 != 0.f) ? s0 / c0 : 0.f;
        o.y = (c1 != 0.f) ? s1 / c1 : 0.f;
        o.z = (c2 != 0.f) ? s2 / c2 : 0.f;
        o.w = (c3 != 0.f) ? s3 / c3 : 0.f;
    }
    ((float4*)(out + (size_t)row * NN))[t] = o;   // tokens 4t..4t+3, coalesced
}

extern "C" void kernel_launch(void* const* d_in, const int* in_sizes, int n_in,
                              void* d_out, int out_size, void* d_ws, size_t ws_size,
                              hipStream_t stream) {
    const float* x   = (const float*)d_in[0];
    const int*   dur = (const int*)d_in[1];
    float*       out = (float*)d_out;
    fused_kernel<<<BB * NF, 256, 0, stream>>>(x, dur, out);
}